// Round 2
// baseline (273.532 us; speedup 1.0000x reference)
//
#include <hip/hip_runtime.h>
#include <hip/hip_bf16.h>

typedef short bf16x8 __attribute__((ext_vector_type(8)));
typedef float f32x4 __attribute__((ext_vector_type(4)));
typedef unsigned short u16;

constexpr int TOKS = 2048;
constexpr int EMB  = 2048;
constexpr int NH   = 16;
constexpr int HS   = 128;
constexpr float RSQ = 0.08838834764831845f; // 1/sqrt(128)

// workspace layout (bytes)
constexpr size_t OFF_SCAL = 0;                       // 4 floats (absmax)
constexpr size_t OFF_QX   = 1024;
constexpr size_t SZ_MAT   = (size_t)TOKS * EMB * 2;  // 8MB bf16
constexpr size_t OFF_QW   = OFF_QX + SZ_MAT;         // 3 mats
constexpr size_t OFF_Q    = OFF_QW + 3 * SZ_MAT;
constexpr size_t OFF_K    = OFF_Q + SZ_MAT;
constexpr size_t OFF_V    = OFF_K + SZ_MAT;
constexpr size_t OFF_VT   = OFF_V + SZ_MAT;
constexpr size_t OFF_DEN  = OFF_VT + SZ_MAT;         // 16MB f32

#define VMCNT(n) asm volatile("s_waitcnt vmcnt(" #n ")" ::: "memory")
#define LGKM0()  asm volatile("s_waitcnt lgkmcnt(0)" ::: "memory")
#define BAR()    do { asm volatile("" ::: "memory"); __builtin_amdgcn_s_barrier(); asm volatile("" ::: "memory"); } while (0)

__device__ __forceinline__ u16 f2b(float f) {
  unsigned u = __float_as_uint(f);
  unsigned r = (u + 0x7fffu + ((u >> 16) & 1u)) >> 16;
  return (u16)r;
}

__device__ __forceinline__ void gload16(const void* g, void* l) {
  __builtin_amdgcn_global_load_lds(
      (const __attribute__((address_space(1))) unsigned int*)g,
      (__attribute__((address_space(3))) unsigned int*)l, 16, 0, 0);
}

__global__ void k_init(int* scal) {
  if (threadIdx.x < 4) scal[threadIdx.x] = 0;
}

__global__ void k_absmax(const float* __restrict__ x, const float* __restrict__ w1,
                         const float* __restrict__ w2, const float* __restrict__ w3,
                         int* scal) {
  const float* src = (blockIdx.y == 0) ? x : (blockIdx.y == 1) ? w1 : (blockIdx.y == 2) ? w2 : w3;
  const float4* s4 = (const float4*)src;
  int idx = blockIdx.x * 256 + threadIdx.x;
  float m = 0.f;
  for (int i = 0; i < 16; ++i) {
    float4 v = s4[idx + i * 65536];
    m = fmaxf(m, fmaxf(fmaxf(fabsf(v.x), fabsf(v.y)), fmaxf(fabsf(v.z), fabsf(v.w))));
  }
  for (int o = 32; o; o >>= 1) m = fmaxf(m, __shfl_down(m, o));
  __shared__ float red[4];
  if ((threadIdx.x & 63) == 0) red[threadIdx.x >> 6] = m;
  __syncthreads();
  if (threadIdx.x == 0) {
    m = fmaxf(fmaxf(red[0], red[1]), fmaxf(red[2], red[3]));
    atomicMax(&scal[blockIdx.y], __float_as_int(m));
  }
}

__global__ void k_quant(const float* __restrict__ x, const float* __restrict__ w1,
                        const float* __restrict__ w2, const float* __restrict__ w3,
                        u16* qx, u16* qw, const int* scal) {
  int a = blockIdx.y;
  const float* src = (a == 0) ? x : (a == 1) ? w1 : (a == 2) ? w2 : w3;
  u16* dst = (a == 0) ? qx : qw + (size_t)(a - 1) * TOKS * EMB;
  float mx = __int_as_float(scal[a]);
  float s = (a == 0) ? mx * 0.25f : mx / 3.0f;
  float lo = (a == 0) ? -4.f : -3.f;
  const float hi = 3.f;
  int idx = blockIdx.x * 256 + threadIdx.x;
  for (int i = 0; i < 16; ++i) {
    int j = idx + i * 65536;
    float4 v = ((const float4*)src)[j];
    ushort4 o;
    o.x = f2b(fminf(fmaxf(rintf(v.x / s), lo), hi));
    o.y = f2b(fminf(fmaxf(rintf(v.y / s), lo), hi));
    o.z = f2b(fminf(fmaxf(rintf(v.z / s), lo), hi));
    o.w = f2b(fminf(fmaxf(rintf(v.w / s), lo), hi));
    ((ushort4*)dst)[j] = o;
  }
}

// Fused QKV GEMM (m97 structure): BM=BN=128, BK=64, 4 waves, swizzled LDS.
__global__ __launch_bounds__(256, 3) void k_gemm(const u16* __restrict__ qx, const u16* __restrict__ qw,
    const float* __restrict__ b1, const float* __restrict__ b2, const float* __restrict__ b3,
    const int* __restrict__ scal, u16* qo, u16* ko, u16* vo) {
  int z = blockIdx.z;
  const u16* W = qw + (size_t)z * TOKS * EMB;
  const float* bias = (z == 0) ? b1 : (z == 1) ? b2 : b3;
  u16* out = (z == 0) ? qo : (z == 1) ? ko : vo;
  float sx = __int_as_float(scal[0]) * 0.25f;
  float sw = __int_as_float(scal[1 + z]) / 3.0f;
  float alpha = sx * sw;
  float extra = (z == 0) ? RSQ : 1.0f;
  int t0 = blockIdx.y * 128, o0 = blockIdx.x * 128;
  __shared__ __align__(16) u16 As[128 * 64];  // 16KB, rows of 128B
  __shared__ __align__(16) u16 Bs[128 * 64];
  int tid = threadIdx.x, lane = tid & 63, wid = tid >> 6;
  int mh = (wid >> 1) * 64, nh = (wid & 1) * 64;
  f32x4 acc[4][4] = {};
  const char* Ab = (const char*)qx;
  const char* Bb = (const char*)W;
  for (int kk = 0; kk < 32; ++kk) {
#pragma unroll
    for (int p = 0; p < 4; ++p) {
      int L = p * 4096 + tid * 16;
      int r = L >> 7;
      int s = ((L >> 4) & 7) ^ (r & 7);
      gload16(Ab + (size_t)(t0 + r) * 4096 + kk * 128 + s * 16,
              (char*)As + p * 4096 + wid * 1024);
      gload16(Bb + (size_t)(o0 + r) * 4096 + kk * 128 + s * 16,
              (char*)Bs + p * 4096 + wid * 1024);
    }
    __syncthreads();
#pragma unroll
    for (int ks = 0; ks < 2; ++ks) {
      bf16x8 af[4], bfr[4];
#pragma unroll
      for (int m = 0; m < 4; ++m) {
        int row = mh + m * 16 + (lane & 15);
        int sl = (ks * 4 + (lane >> 4)) ^ (row & 7);
        af[m] = *(const bf16x8*)((const char*)As + row * 128 + sl * 16);
      }
#pragma unroll
      for (int n = 0; n < 4; ++n) {
        int row = nh + n * 16 + (lane & 15);
        int sl = (ks * 4 + (lane >> 4)) ^ (row & 7);
        bfr[n] = *(const bf16x8*)((const char*)Bs + row * 128 + sl * 16);
      }
#pragma unroll
      for (int m = 0; m < 4; ++m)
#pragma unroll
        for (int n = 0; n < 4; ++n)
          acc[m][n] = __builtin_amdgcn_mfma_f32_16x16x32_bf16(af[m], bfr[n], acc[m][n], 0, 0, 0);
    }
    __syncthreads();
  }
#pragma unroll
  for (int m = 0; m < 4; ++m)
#pragma unroll
    for (int n = 0; n < 4; ++n) {
      int ocol = o0 + nh + n * 16 + (lane & 15);
      int h = ocol >> 7, d = ocol & 127;
      float bb = bias[ocol];
#pragma unroll
      for (int r = 0; r < 4; ++r) {
        int trow = t0 + mh + m * 16 + (lane >> 4) * 4 + r;
        float v = (acc[m][n][r] * alpha + bb) * extra;
        out[(size_t)(h * TOKS + trow) * HS + d] = f2b(v);
      }
    }
}

__global__ void k_transpose(const u16* __restrict__ v, u16* vt) {
  int h = blockIdx.z, d0 = blockIdx.y * 64, t0 = blockIdx.x * 64;
  __shared__ u16 tile[64][65];
  int tid = threadIdx.x;
  for (int i = 0; i < 16; ++i) {
    int idx = i * 256 + tid, r = idx >> 6, c = idx & 63;
    tile[r][c] = v[(size_t)(h * TOKS + t0 + r) * HS + d0 + c];
  }
  __syncthreads();
  for (int i = 0; i < 16; ++i) {
    int idx = i * 256 + tid, r = idx >> 6, c = idx & 63;
    vt[(size_t)(h * HS + d0 + r) * TOKS + t0 + c] = tile[c][r];
  }
}

// denom: invden[q,k] = 1 / sum_h exp(att[h,q,k]); 64q x 64k per block, 4 waves split k.
__global__ __launch_bounds__(256, 4) void k_denom(const u16* __restrict__ q, const u16* __restrict__ k,
                                                  float* __restrict__ invden) {
  int kt0 = blockIdx.x * 64, qt0 = blockIdx.y * 64;
  __shared__ __align__(16) u16 Ks[2][64 * 128];  // 2 x 16KB, rows of 256B, swizzled
  int tid = threadIdx.x, lane = tid & 63, wid = tid >> 6;
  f32x4 den[4] = {};
  auto stageK = [&](int h, int buf) {
#pragma unroll
    for (int p = 0; p < 4; ++p) {
      int L = p * 4096 + tid * 16;
      int r = L >> 8;
      int s = ((L >> 4) & 15) ^ (r & 7);
      gload16((const char*)k + (size_t)(h * TOKS + kt0 + r) * 256 + s * 16,
              (char*)Ks[buf] + p * 4096 + wid * 1024);
    }
  };
  stageK(0, 0);
  for (int h = 0; h < NH; ++h) {
    int cur = h & 1;
    if (h < NH - 1) { stageK(h + 1, cur ^ 1); VMCNT(4); } else { VMCNT(0); }
    BAR();
    f32x4 pacc[4] = {};
#pragma unroll
    for (int c = 0; c < 4; ++c) {
      int row = wid * 16 + (lane & 15);
      int sl = (c * 4 + (lane >> 4)) ^ (row & 7);
      bf16x8 bk = *(const bf16x8*)((const char*)Ks[cur] + row * 256 + sl * 16);
#pragma unroll
      for (int m = 0; m < 4; ++m) {
        bf16x8 aq = *(const bf16x8*)(q + (size_t)(h * TOKS + qt0 + m * 16 + (lane & 15)) * HS
                                     + c * 32 + (lane >> 4) * 8);
        pacc[m] = __builtin_amdgcn_mfma_f32_16x16x32_bf16(aq, bk, pacc[m], 0, 0, 0);
      }
    }
#pragma unroll
    for (int m = 0; m < 4; ++m)
#pragma unroll
      for (int r = 0; r < 4; ++r) den[m][r] += __expf(pacc[m][r]);
    BAR();
  }
#pragma unroll
  for (int m = 0; m < 4; ++m)
#pragma unroll
    for (int r = 0; r < 4; ++r) {
      int qrow = qt0 + m * 16 + (lane >> 4) * 4 + r;
      int kcol = kt0 + wid * 16 + (lane & 15);
      invden[(size_t)qrow * TOKS + kcol] = 1.0f / den[m][r];
    }
}

// attention: 64q x 1 head per block; 4 waves split k (QK^T) / d (PV); Q hoisted.
__global__ __launch_bounds__(256, 2) void k_attn(const u16* __restrict__ q, const u16* __restrict__ k,
                                                 const u16* __restrict__ vt, const float* __restrict__ invden,
                                                 float* __restrict__ out) {
  int qt0 = blockIdx.x * 64, h = blockIdx.y;
  __shared__ __align__(16) u16 Ks[2][64 * 128];   // 2 x 16KB, rows = k-token (256B)
  __shared__ __align__(16) u16 Vs[2][128 * 64];   // 2 x 16KB, rows = d (128B of 64 k-vals)
  __shared__ __align__(16) u16 Ps[64 * 64];       // 8KB, rows = q (128B of 64 k-vals)
  int tid = threadIdx.x, lane = tid & 63, wid = tid >> 6;

  auto stageKV = [&](int kb, int buf) {
#pragma unroll
    for (int p = 0; p < 4; ++p) {  // K first (waited at vmcnt(12))
      int L = p * 4096 + tid * 16;
      int r = L >> 8;
      int s = ((L >> 4) & 15) ^ (r & 7);
      gload16((const char*)k + (size_t)(h * TOKS + kb * 64 + r) * 256 + s * 16,
              (char*)Ks[buf] + p * 4096 + wid * 1024);
    }
#pragma unroll
    for (int p = 0; p < 4; ++p) {  // V second (waited at vmcnt(8))
      int L = p * 4096 + tid * 16;
      int r = L >> 7;
      int s = ((L >> 4) & 7) ^ (r & 7);
      gload16((const char*)vt + (size_t)(h * HS + r) * 4096 + kb * 128 + s * 16,
              (char*)Vs[buf] + p * 4096 + wid * 1024);
    }
  };
  stageKV(0, 0);
  bf16x8 qf[4][4];
#pragma unroll
  for (int m = 0; m < 4; ++m)
#pragma unroll
    for (int c = 0; c < 4; ++c)
      qf[m][c] = *(const bf16x8*)(q + (size_t)(h * TOKS + qt0 + m * 16 + (lane & 15)) * HS
                                  + c * 32 + (lane >> 4) * 8);
  f32x4 yacc[4][2] = {};
  const float* dinv = invden + (size_t)qt0 * TOKS;
  for (int kb = 0; kb < 32; ++kb) {
    int cur = kb & 1;
    if (kb < 31) { stageKV(kb + 1, cur ^ 1); VMCNT(12); } else { VMCNT(4); }
    BAR();  // K[cur] ready everywhere
    f32x4 pacc[4] = {};
#pragma unroll
    for (int c = 0; c < 4; ++c) {
      int row = wid * 16 + (lane & 15);
      int sl = (c * 4 + (lane >> 4)) ^ (row & 7);
      bf16x8 bk = *(const bf16x8*)((const char*)Ks[cur] + row * 256 + sl * 16);
#pragma unroll
      for (int m = 0; m < 4; ++m)
        pacc[m] = __builtin_amdgcn_mfma_f32_16x16x32_bf16(qf[m][c], bk, pacc[m], 0, 0, 0);
    }
#pragma unroll
    for (int m = 0; m < 4; ++m)
#pragma unroll
      for (int r = 0; r < 4; ++r) {
        int qr = m * 16 + (lane >> 4) * 4 + r;
        int kc = kb * 64 + wid * 16 + (lane & 15);
        float e = __expf(pacc[m][r]) * dinv[(size_t)qr * TOKS + kc];
        int col = wid * 16 + (lane & 15);
        int psl = (col >> 3) ^ (qr & 7);
        *(u16*)((char*)Ps + qr * 128 + psl * 16 + (col & 7) * 2) = f2b(e);
      }
    if (kb < 31) { VMCNT(8); } else { VMCNT(0); }
    LGKM0();
    BAR();  // V[cur] ready + Ps visible to all waves
#pragma unroll
    for (int ks = 0; ks < 2; ++ks) {
      bf16x8 pa[4], bv[2];
#pragma unroll
      for (int m = 0; m < 4; ++m) {
        int row = m * 16 + (lane & 15);
        int sl = (ks * 4 + (lane >> 4)) ^ (row & 7);
        pa[m] = *(const bf16x8*)((const char*)Ps + row * 128 + sl * 16);
      }
#pragma unroll
      for (int j = 0; j < 2; ++j) {
        int row = wid * 32 + j * 16 + (lane & 15);
        int sl = (ks * 4 + (lane >> 4)) ^ (row & 7);
        bv[j] = *(const bf16x8*)((const char*)Vs[cur] + row * 128 + sl * 16);
      }
#pragma unroll
      for (int m = 0; m < 4; ++m)
#pragma unroll
        for (int j = 0; j < 2; ++j)
          yacc[m][j] = __builtin_amdgcn_mfma_f32_16x16x32_bf16(pa[m], bv[j], yacc[m][j], 0, 0, 0);
    }
    BAR();  // all reads of Ps/Ks[cur]/Vs[cur] done before next iter overwrites
  }
#pragma unroll
  for (int m = 0; m < 4; ++m)
#pragma unroll
    for (int j = 0; j < 2; ++j)
#pragma unroll
      for (int r = 0; r < 4; ++r) {
        int trow = qt0 + m * 16 + (lane >> 4) * 4 + r;
        int dcol = wid * 32 + j * 16 + (lane & 15);
        out[(size_t)(h * TOKS + trow) * HS + dcol] = yacc[m][j][r];
      }
}

extern "C" void kernel_launch(void* const* d_in, const int* in_sizes, int n_in,
                              void* d_out, int out_size, void* d_ws, size_t ws_size,
                              hipStream_t stream) {
  const float* x  = (const float*)d_in[0];
  const float* W1 = (const float*)d_in[1];
  const float* b1 = (const float*)d_in[2];
  const float* W2 = (const float*)d_in[3];
  const float* b2 = (const float*)d_in[4];
  const float* W3 = (const float*)d_in[5];
  const float* b3 = (const float*)d_in[6];
  char* ws = (char*)d_ws;
  int*   scal   = (int*)(ws + OFF_SCAL);
  u16*   qx     = (u16*)(ws + OFF_QX);
  u16*   qw     = (u16*)(ws + OFF_QW);
  u16*   qo     = (u16*)(ws + OFF_Q);
  u16*   ko     = (u16*)(ws + OFF_K);
  u16*   vo     = (u16*)(ws + OFF_V);
  u16*   vt     = (u16*)(ws + OFF_VT);
  float* invden = (float*)(ws + OFF_DEN);
  float* y      = (float*)d_out;

  hipLaunchKernelGGL(k_init, dim3(1), dim3(64), 0, stream, scal);
  hipLaunchKernelGGL(k_absmax, dim3(256, 4), dim3(256), 0, stream, x, W1, W2, W3, scal);
  hipLaunchKernelGGL(k_quant, dim3(256, 4), dim3(256), 0, stream, x, W1, W2, W3, qx, qw, scal);
  hipLaunchKernelGGL(k_gemm, dim3(16, 16, 3), dim3(256), 0, stream,
                     qx, qw, b1, b2, b3, scal, qo, ko, vo);
  hipLaunchKernelGGL(k_transpose, dim3(32, 2, 16), dim3(256), 0, stream, vo, vt);
  hipLaunchKernelGGL(k_denom, dim3(32, 32), dim3(256), 0, stream, qo, ko, invden);
  hipLaunchKernelGGL(k_attn, dim3(32, 16), dim3(256), 0, stream, qo, ko, vt, invden, y);
}

// Round 3
// 191.865 us; speedup vs baseline: 1.4256x; 1.4256x over previous
//
#include <hip/hip_runtime.h>
#include <hip/hip_bf16.h>

typedef short bf16x8 __attribute__((ext_vector_type(8)));
typedef float f32x4 __attribute__((ext_vector_type(4)));
typedef unsigned short u16;

constexpr int TOKS = 2048;
constexpr int EMB  = 2048;
constexpr int NH   = 16;
constexpr int HS   = 128;
constexpr float RSQ = 0.08838834764831845f; // 1/sqrt(128)

// workspace layout (bytes) — 80MB total, same footprint as round 1/2
constexpr size_t OFF_SCAL = 0;                       // 4 floats (absmax)
constexpr size_t OFF_QX   = 1024;
constexpr size_t SZ_MAT   = (size_t)TOKS * EMB * 2;  // 8MB bf16
constexpr size_t OFF_QW   = OFF_QX + SZ_MAT;         // 3 mats (24MB)
constexpr size_t OFF_Q    = OFF_QW + 3 * SZ_MAT;
constexpr size_t OFF_K    = OFF_Q + SZ_MAT;
constexpr size_t OFF_V    = OFF_K + SZ_MAT;
constexpr size_t OFF_VT   = OFF_V + SZ_MAT;
constexpr size_t OFF_DEN  = OFF_VT + SZ_MAT;         // invden, 16MB f32
// den0/den1 (16MB each) overlay qx/qw — those are dead after k_gemm
constexpr size_t OFF_DEN0 = OFF_QX;
constexpr size_t OFF_DEN1 = OFF_QX + (size_t)TOKS * TOKS * 4;

#define VMCNT(n) asm volatile("s_waitcnt vmcnt(" #n ")" ::: "memory")
#define LGKM0()  asm volatile("s_waitcnt lgkmcnt(0)" ::: "memory")
#define BAR()    do { asm volatile("" ::: "memory"); __builtin_amdgcn_s_barrier(); asm volatile("" ::: "memory"); } while (0)

__device__ __forceinline__ u16 f2b(float f) {
  unsigned u = __float_as_uint(f);
  unsigned r = (u + 0x7fffu + ((u >> 16) & 1u)) >> 16;
  return (u16)r;
}

__device__ __forceinline__ void gload16(const void* g, void* l) {
  __builtin_amdgcn_global_load_lds(
      (const __attribute__((address_space(1))) unsigned int*)g,
      (__attribute__((address_space(3))) unsigned int*)l, 16, 0, 0);
}

__global__ void k_init(int* scal) {
  if (threadIdx.x < 4) scal[threadIdx.x] = 0;
}

__global__ void k_absmax(const float* __restrict__ x, const float* __restrict__ w1,
                         const float* __restrict__ w2, const float* __restrict__ w3,
                         int* scal) {
  const float* src = (blockIdx.y == 0) ? x : (blockIdx.y == 1) ? w1 : (blockIdx.y == 2) ? w2 : w3;
  const float4* s4 = (const float4*)src;
  int idx = blockIdx.x * 256 + threadIdx.x;
  float m = 0.f;
  for (int i = 0; i < 16; ++i) {
    float4 v = s4[idx + i * 65536];
    m = fmaxf(m, fmaxf(fmaxf(fabsf(v.x), fabsf(v.y)), fmaxf(fabsf(v.z), fabsf(v.w))));
  }
  for (int o = 32; o; o >>= 1) m = fmaxf(m, __shfl_down(m, o));
  __shared__ float red[4];
  if ((threadIdx.x & 63) == 0) red[threadIdx.x >> 6] = m;
  __syncthreads();
  if (threadIdx.x == 0) {
    m = fmaxf(fmaxf(red[0], red[1]), fmaxf(red[2], red[3]));
    atomicMax(&scal[blockIdx.y], __float_as_int(m));
  }
}

__global__ void k_quant(const float* __restrict__ x, const float* __restrict__ w1,
                        const float* __restrict__ w2, const float* __restrict__ w3,
                        u16* qx, u16* qw, const int* scal) {
  int a = blockIdx.y;
  const float* src = (a == 0) ? x : (a == 1) ? w1 : (a == 2) ? w2 : w3;
  u16* dst = (a == 0) ? qx : qw + (size_t)(a - 1) * TOKS * EMB;
  float mx = __int_as_float(scal[a]);
  float s = (a == 0) ? mx * 0.25f : mx / 3.0f;
  float lo = (a == 0) ? -4.f : -3.f;
  const float hi = 3.f;
  int idx = blockIdx.x * 256 + threadIdx.x;
  for (int i = 0; i < 16; ++i) {
    int j = idx + i * 65536;
    float4 v = ((const float4*)src)[j];
    ushort4 o;
    o.x = f2b(fminf(fmaxf(rintf(v.x / s), lo), hi));
    o.y = f2b(fminf(fmaxf(rintf(v.y / s), lo), hi));
    o.z = f2b(fminf(fmaxf(rintf(v.z / s), lo), hi));
    o.w = f2b(fminf(fmaxf(rintf(v.w / s), lo), hi));
    ((ushort4*)dst)[j] = o;
  }
}

// Fused QKV GEMM: out[t, o] in token-major [T, EMB] layout.
__global__ __launch_bounds__(256, 3) void k_gemm(const u16* __restrict__ qx, const u16* __restrict__ qw,
    const float* __restrict__ b1, const float* __restrict__ b2, const float* __restrict__ b3,
    const int* __restrict__ scal, u16* qo, u16* ko, u16* vo) {
  int z = blockIdx.z;
  const u16* W = qw + (size_t)z * TOKS * EMB;
  const float* bias = (z == 0) ? b1 : (z == 1) ? b2 : b3;
  u16* out = (z == 0) ? qo : (z == 1) ? ko : vo;
  float sx = __int_as_float(scal[0]) * 0.25f;
  float sw = __int_as_float(scal[1 + z]) / 3.0f;
  float alpha = sx * sw;
  float extra = (z == 0) ? RSQ : 1.0f;
  int t0 = blockIdx.y * 128, o0 = blockIdx.x * 128;
  __shared__ __align__(16) u16 As[128 * 64];  // 16KB, rows of 128B
  __shared__ __align__(16) u16 Bs[128 * 64];
  int tid = threadIdx.x, lane = tid & 63, wid = tid >> 6;
  int mh = (wid >> 1) * 64, nh = (wid & 1) * 64;
  f32x4 acc[4][4] = {};
  const char* Ab = (const char*)qx;
  const char* Bb = (const char*)W;
  for (int kk = 0; kk < 32; ++kk) {
#pragma unroll
    for (int p = 0; p < 4; ++p) {
      int L = p * 4096 + tid * 16;
      int r = L >> 7;
      int s = ((L >> 4) & 7) ^ (r & 7);
      gload16(Ab + (size_t)(t0 + r) * 4096 + kk * 128 + s * 16,
              (char*)As + p * 4096 + wid * 1024);
      gload16(Bb + (size_t)(o0 + r) * 4096 + kk * 128 + s * 16,
              (char*)Bs + p * 4096 + wid * 1024);
    }
    __syncthreads();
#pragma unroll
    for (int ks = 0; ks < 2; ++ks) {
      bf16x8 af[4], bfr[4];
#pragma unroll
      for (int m = 0; m < 4; ++m) {
        int row = mh + m * 16 + (lane & 15);
        int sl = (ks * 4 + (lane >> 4)) ^ (row & 7);
        af[m] = *(const bf16x8*)((const char*)As + row * 128 + sl * 16);
      }
#pragma unroll
      for (int n = 0; n < 4; ++n) {
        int row = nh + n * 16 + (lane & 15);
        int sl = (ks * 4 + (lane >> 4)) ^ (row & 7);
        bfr[n] = *(const bf16x8*)((const char*)Bs + row * 128 + sl * 16);
      }
#pragma unroll
      for (int m = 0; m < 4; ++m)
#pragma unroll
        for (int n = 0; n < 4; ++n)
          acc[m][n] = __builtin_amdgcn_mfma_f32_16x16x32_bf16(af[m], bfr[n], acc[m][n], 0, 0, 0);
    }
    __syncthreads();
  }
#pragma unroll
  for (int m = 0; m < 4; ++m)
#pragma unroll
    for (int n = 0; n < 4; ++n) {
      int ocol = o0 + nh + n * 16 + (lane & 15);
      float bb = bias[ocol];
#pragma unroll
      for (int r = 0; r < 4; ++r) {
        int trow = t0 + mh + m * 16 + (lane >> 4) * 4 + r;
        float v = (acc[m][n][r] * alpha + bb) * extra;
        out[(size_t)trow * EMB + ocol] = f2b(v);
      }
    }
}

__global__ void k_transpose(const u16* __restrict__ v, u16* vt) {
  int h = blockIdx.z, d0 = blockIdx.y * 64, t0 = blockIdx.x * 64;
  __shared__ u16 tile[64][65];
  int tid = threadIdx.x;
  for (int i = 0; i < 16; ++i) {
    int idx = i * 256 + tid, r = idx >> 6, c = idx & 63;
    tile[r][c] = v[(size_t)(t0 + r) * EMB + h * HS + d0 + c];
  }
  __syncthreads();
  for (int i = 0; i < 16; ++i) {
    int idx = i * 256 + tid, r = idx >> 6, c = idx & 63;
    vt[(size_t)(h * HS + d0 + r) * TOKS + t0 + c] = tile[c][r];
  }
}

// denom partial: den[q,k] = sum_{h in group} exp(att[h,q,k])
// GEMM-with-exp: 128x128 tile, 4 waves of 64x64, dbuf LDS, counted vmcnt.
// K-loop = 8 heads x 2 chunks of BK=64; exp+accumulate at each head boundary.
__global__ __launch_bounds__(256, 2) void k_denom(const u16* __restrict__ q, const u16* __restrict__ k,
                                                  float* __restrict__ den0, float* __restrict__ den1) {
  int kt0 = blockIdx.x * 128, qt0 = blockIdx.y * 128, hg = blockIdx.z;
  float* den = hg ? den1 : den0;
  __shared__ __align__(16) u16 As[2][128 * 64];  // 2 x 16KB
  __shared__ __align__(16) u16 Bs[2][128 * 64];
  int tid = threadIdx.x, lane = tid & 63, wid = tid >> 6;
  int mh = (wid >> 1) * 64, nh = (wid & 1) * 64;
  f32x4 acc[4][4] = {}, dd[4][4] = {};
  auto stage = [&](int st, int buf) {
    int cb = hg * 2048 + st * 128;  // byte offset of this 64-col chunk
#pragma unroll
    for (int p = 0; p < 4; ++p) {
      int L = p * 4096 + tid * 16;
      int r = L >> 7;
      int s = ((L >> 4) & 7) ^ (r & 7);
      gload16((const char*)q + (size_t)(qt0 + r) * 4096 + cb + s * 16,
              (char*)As[buf] + p * 4096 + wid * 1024);
      gload16((const char*)k + (size_t)(kt0 + r) * 4096 + cb + s * 16,
              (char*)Bs[buf] + p * 4096 + wid * 1024);
    }
  };
  stage(0, 0);
  for (int st = 0; st < 16; ++st) {
    int cur = st & 1;
    if (st < 15) { stage(st + 1, cur ^ 1); VMCNT(8); } else { VMCNT(0); }
    BAR();
#pragma unroll
    for (int ks = 0; ks < 2; ++ks) {
      bf16x8 af[4], bfr[4];
#pragma unroll
      for (int m = 0; m < 4; ++m) {
        int row = mh + m * 16 + (lane & 15);
        int sl = (ks * 4 + (lane >> 4)) ^ (row & 7);
        af[m] = *(const bf16x8*)((const char*)As[cur] + row * 128 + sl * 16);
      }
#pragma unroll
      for (int n = 0; n < 4; ++n) {
        int row = nh + n * 16 + (lane & 15);
        int sl = (ks * 4 + (lane >> 4)) ^ (row & 7);
        bfr[n] = *(const bf16x8*)((const char*)Bs[cur] + row * 128 + sl * 16);
      }
#pragma unroll
      for (int m = 0; m < 4; ++m)
#pragma unroll
        for (int n = 0; n < 4; ++n)
          acc[m][n] = __builtin_amdgcn_mfma_f32_16x16x32_bf16(af[m], bfr[n], acc[m][n], 0, 0, 0);
    }
    BAR();
    if (st & 1) {  // head boundary: fold exp(acc) into dd, reset acc
#pragma unroll
      for (int m = 0; m < 4; ++m)
#pragma unroll
        for (int n = 0; n < 4; ++n) {
#pragma unroll
          for (int r = 0; r < 4; ++r) dd[m][n][r] += __expf(acc[m][n][r]);
          acc[m][n] = f32x4{0.f, 0.f, 0.f, 0.f};
        }
    }
  }
#pragma unroll
  for (int m = 0; m < 4; ++m)
#pragma unroll
    for (int n = 0; n < 4; ++n)
#pragma unroll
      for (int r = 0; r < 4; ++r) {
        int qrow = qt0 + mh + m * 16 + (lane >> 4) * 4 + r;
        int kcol = kt0 + nh + n * 16 + (lane & 15);
        den[(size_t)qrow * TOKS + kcol] = dd[m][n][r];
      }
}

__global__ void k_recip(const float* __restrict__ a, const float* __restrict__ b,
                        float* __restrict__ o) {
  int i = blockIdx.x * 256 + threadIdx.x;
  const float4* a4 = (const float4*)a;
  const float4* b4 = (const float4*)b;
  float4* o4 = (float4*)o;
#pragma unroll
  for (int j = 0; j < 4; ++j) {
    int t = i + j * 262144;
    float4 va = a4[t], vb = b4[t];
    float4 r;
    r.x = 1.0f / (va.x + vb.x);
    r.y = 1.0f / (va.y + vb.y);
    r.z = 1.0f / (va.z + vb.z);
    r.w = 1.0f / (va.w + vb.w);
    o4[t] = r;
  }
}

// attention: 64q x 1 head per block; 4 waves split k (QK^T) / d (PV); Q hoisted.
// q,k in [T, EMB] token-major; vt in [h][d][t].
__global__ __launch_bounds__(256, 2) void k_attn(const u16* __restrict__ q, const u16* __restrict__ k,
                                                 const u16* __restrict__ vt, const float* __restrict__ invden,
                                                 float* __restrict__ out) {
  int qt0 = blockIdx.x * 64, h = blockIdx.y;
  __shared__ __align__(16) u16 Ks[2][64 * 128];   // 2 x 16KB, rows = k-token (256B)
  __shared__ __align__(16) u16 Vs[2][128 * 64];   // 2 x 16KB, rows = d (128B of 64 k-vals)
  __shared__ __align__(16) u16 Ps[64 * 64];       // 8KB, rows = q (128B of 64 k-vals)
  int tid = threadIdx.x, lane = tid & 63, wid = tid >> 6;

  auto stageKV = [&](int kb, int buf) {
#pragma unroll
    for (int p = 0; p < 4; ++p) {  // K first (drained at vmcnt(12))
      int L = p * 4096 + tid * 16;
      int r = L >> 8;
      int s = ((L >> 4) & 15) ^ (r & 7);
      gload16((const char*)k + (size_t)(kb * 64 + r) * 4096 + h * 256 + s * 16,
              (char*)Ks[buf] + p * 4096 + wid * 1024);
    }
#pragma unroll
    for (int p = 0; p < 4; ++p) {  // V second (drained at vmcnt(8))
      int L = p * 4096 + tid * 16;
      int r = L >> 7;
      int s = ((L >> 4) & 7) ^ (r & 7);
      gload16((const char*)vt + (size_t)(h * HS + r) * 4096 + kb * 128 + s * 16,
              (char*)Vs[buf] + p * 4096 + wid * 1024);
    }
  };
  stageKV(0, 0);
  bf16x8 qf[4][4];
#pragma unroll
  for (int m = 0; m < 4; ++m)
#pragma unroll
    for (int c = 0; c < 4; ++c)
      qf[m][c] = *(const bf16x8*)(q + (size_t)(qt0 + m * 16 + (lane & 15)) * EMB
                                  + h * HS + c * 32 + (lane >> 4) * 8);
  f32x4 yacc[4][2] = {};
  const float* dinv = invden + (size_t)qt0 * TOKS;
  for (int kb = 0; kb < 32; ++kb) {
    int cur = kb & 1;
    if (kb < 31) { stageKV(kb + 1, cur ^ 1); VMCNT(12); } else { VMCNT(4); }
    BAR();  // K[cur] ready everywhere
    f32x4 pacc[4] = {};
#pragma unroll
    for (int c = 0; c < 4; ++c) {
      int row = wid * 16 + (lane & 15);
      int sl = (c * 4 + (lane >> 4)) ^ (row & 7);
      bf16x8 bk = *(const bf16x8*)((const char*)Ks[cur] + row * 256 + sl * 16);
#pragma unroll
      for (int m = 0; m < 4; ++m)
        pacc[m] = __builtin_amdgcn_mfma_f32_16x16x32_bf16(qf[m][c], bk, pacc[m], 0, 0, 0);
    }
#pragma unroll
    for (int m = 0; m < 4; ++m)
#pragma unroll
      for (int r = 0; r < 4; ++r) {
        int qr = m * 16 + (lane >> 4) * 4 + r;
        int kc = kb * 64 + wid * 16 + (lane & 15);
        float e = __expf(pacc[m][r]) * dinv[(size_t)qr * TOKS + kc];
        int col = wid * 16 + (lane & 15);
        int psl = (col >> 3) ^ (qr & 7);
        *(u16*)((char*)Ps + qr * 128 + psl * 16 + (col & 7) * 2) = f2b(e);
      }
    if (kb < 31) { VMCNT(8); } else { VMCNT(0); }
    LGKM0();
    BAR();  // V[cur] ready + Ps visible to all waves
#pragma unroll
    for (int ks = 0; ks < 2; ++ks) {
      bf16x8 pa[4], bv[2];
#pragma unroll
      for (int m = 0; m < 4; ++m) {
        int row = m * 16 + (lane & 15);
        int sl = (ks * 4 + (lane >> 4)) ^ (row & 7);
        pa[m] = *(const bf16x8*)((const char*)Ps + row * 128 + sl * 16);
      }
#pragma unroll
      for (int j = 0; j < 2; ++j) {
        int row = wid * 32 + j * 16 + (lane & 15);
        int sl = (ks * 4 + (lane >> 4)) ^ (row & 7);
        bv[j] = *(const bf16x8*)((const char*)Vs[cur] + row * 128 + sl * 16);
      }
#pragma unroll
      for (int m = 0; m < 4; ++m)
#pragma unroll
        for (int j = 0; j < 2; ++j)
          yacc[m][j] = __builtin_amdgcn_mfma_f32_16x16x32_bf16(pa[m], bv[j], yacc[m][j], 0, 0, 0);
    }
    BAR();  // all reads of Ps/Ks[cur]/Vs[cur] done before next iter overwrites
  }
#pragma unroll
  for (int m = 0; m < 4; ++m)
#pragma unroll
    for (int j = 0; j < 2; ++j)
#pragma unroll
      for (int r = 0; r < 4; ++r) {
        int trow = qt0 + m * 16 + (lane >> 4) * 4 + r;
        int dcol = wid * 32 + j * 16 + (lane & 15);
        out[(size_t)(h * TOKS + trow) * HS + dcol] = yacc[m][j][r];
      }
}

extern "C" void kernel_launch(void* const* d_in, const int* in_sizes, int n_in,
                              void* d_out, int out_size, void* d_ws, size_t ws_size,
                              hipStream_t stream) {
  const float* x  = (const float*)d_in[0];
  const float* W1 = (const float*)d_in[1];
  const float* b1 = (const float*)d_in[2];
  const float* W2 = (const float*)d_in[3];
  const float* b2 = (const float*)d_in[4];
  const float* W3 = (const float*)d_in[5];
  const float* b3 = (const float*)d_in[6];
  char* ws = (char*)d_ws;
  int*   scal   = (int*)(ws + OFF_SCAL);
  u16*   qx     = (u16*)(ws + OFF_QX);
  u16*   qw     = (u16*)(ws + OFF_QW);
  u16*   qo     = (u16*)(ws + OFF_Q);
  u16*   ko     = (u16*)(ws + OFF_K);
  u16*   vo     = (u16*)(ws + OFF_V);
  u16*   vt     = (u16*)(ws + OFF_VT);
  float* den0   = (float*)(ws + OFF_DEN0);
  float* den1   = (float*)(ws + OFF_DEN1);
  float* invden = (float*)(ws + OFF_DEN);
  float* y      = (float*)d_out;

  hipLaunchKernelGGL(k_init, dim3(1), dim3(64), 0, stream, scal);
  hipLaunchKernelGGL(k_absmax, dim3(256, 4), dim3(256), 0, stream, x, W1, W2, W3, scal);
  hipLaunchKernelGGL(k_quant, dim3(256, 4), dim3(256), 0, stream, x, W1, W2, W3, qx, qw, scal);
  hipLaunchKernelGGL(k_gemm, dim3(16, 16, 3), dim3(256), 0, stream,
                     qx, qw, b1, b2, b3, scal, qo, ko, vo);
  hipLaunchKernelGGL(k_transpose, dim3(32, 2, 16), dim3(256), 0, stream, vo, vt);
  hipLaunchKernelGGL(k_denom, dim3(16, 16, 2), dim3(256), 0, stream, qo, ko, den0, den1);
  hipLaunchKernelGGL(k_recip, dim3(1024), dim3(256), 0, stream, den0, den1, invden);
  hipLaunchKernelGGL(k_attn, dim3(32, 16), dim3(256), 0, stream, qo, ko, vt, invden, y);
}